// Round 1
// baseline (309.779 us; speedup 1.0000x reference)
//
#include <hip/hip_runtime.h>
#include <stdint.h>
#include <math.h>

// Problem constants (fixed by the reference)
constexpr int CB = 2;      // batch
constexpr int CS = 2048;   // seq (cutoff)
constexpr int CD = 1024;   // dmodel
constexpr int CE = 16;     // experts
constexpr int CK = 256;    // topk

typedef short bf16x8 __attribute__((ext_vector_type(8)));
typedef float f32x4 __attribute__((ext_vector_type(4)));

__device__ inline unsigned short f2bf(float f) {
    union { float f; uint32_t u; } v; v.f = f;
    uint32_t u = v.u;
    uint32_t r = (u + 0x7FFFu + ((u >> 16) & 1u)) >> 16;
    return (unsigned short)r;
}

// ---------------- K1: logits[b,s,e] = dot(x[b,s,:], gate[:,e]) ----------------
// one wave per token
__global__ void logits_kernel(const float* __restrict__ x,
                              const float* __restrict__ gate,
                              float* __restrict__ logits) {
    const int bs = blockIdx.x;      // 0..B*S-1
    const int l = threadIdx.x;      // 0..63
    const float* xr = x + (size_t)bs * CD;
    float acc[CE];
#pragma unroll
    for (int e = 0; e < CE; e++) acc[e] = 0.0f;
    for (int i = 0; i < CD / 64; i++) {
        const int d = i * 64 + l;
        const float xv = xr[d];
        const float* g = gate + (size_t)d * CE;
#pragma unroll
        for (int e = 0; e < CE; e++) acc[e] += xv * g[e];
    }
#pragma unroll
    for (int e = 0; e < CE; e++) {
        float v = acc[e];
#pragma unroll
        for (int o = 32; o > 0; o >>= 1) v += __shfl_down(v, o);
        if (l == 0) logits[(size_t)bs * CE + e] = v;
    }
}

// ---------------- K2: per (b,e) softmax over tokens + top-256 ----------------
__global__ void topk_kernel(const float* __restrict__ logits,
                            int* __restrict__ idx_out,
                            float* __restrict__ g_out) {
    const int be = blockIdx.x;            // b*E + e
    const int b = be >> 4, e = be & 15;
    const int tid = threadIdx.x;          // 256
    const int lane = tid & 63, wid = tid >> 6;

    __shared__ float redf[4];
    __shared__ int redi[4];
    __shared__ int scnt, eqc;
    __shared__ int eqbuf[CS];

    float lv[8], p[8];
    unsigned int uv[8];
#pragma unroll
    for (int j = 0; j < 8; j++) {
        const int s = tid + j * 256;
        lv[j] = logits[((size_t)(b * CS + s)) * CE + e];
    }
    // block max
    float m = lv[0];
#pragma unroll
    for (int j = 1; j < 8; j++) m = fmaxf(m, lv[j]);
#pragma unroll
    for (int o = 32; o > 0; o >>= 1) m = fmaxf(m, __shfl_down(m, o));
    if (lane == 0) redf[wid] = m;
    __syncthreads();
    m = fmaxf(fmaxf(redf[0], redf[1]), fmaxf(redf[2], redf[3]));
    __syncthreads();
    // exp + sum
    float lsum = 0.0f;
#pragma unroll
    for (int j = 0; j < 8; j++) {
        p[j] = expf(lv[j] - m);
        uv[j] = __float_as_uint(p[j]);
        lsum += p[j];
    }
#pragma unroll
    for (int o = 32; o > 0; o >>= 1) lsum += __shfl_down(lsum, o);
    if (lane == 0) redf[wid] = lsum;
    __syncthreads();
    const float total = redf[0] + redf[1] + redf[2] + redf[3];
    const float inv_total = 1.0f / total;
    __syncthreads();

    // binary search for v = 256th largest bit-pattern (p > 0 so uint order == float order)
    unsigned int lo = 0u, hi = 0xFFFFFFFFu;
    while (lo < hi) {
        const unsigned int mid = lo + ((hi - lo) >> 1) + 1u;
        int c = 0;
#pragma unroll
        for (int j = 0; j < 8; j++) c += (uv[j] >= mid) ? 1 : 0;
#pragma unroll
        for (int o = 32; o > 0; o >>= 1) c += __shfl_down(c, o);
        if (lane == 0) redi[wid] = c;
        __syncthreads();
        c = redi[0] + redi[1] + redi[2] + redi[3];
        __syncthreads();
        if (c >= CK) lo = mid; else hi = mid - 1u;
    }
    const unsigned int v = lo;

    if (tid == 0) { scnt = 0; eqc = 0; }
    __syncthreads();
#pragma unroll
    for (int j = 0; j < 8; j++) {
        const int s = tid + j * 256;
        if (uv[j] > v) {
            const int pos = atomicAdd(&scnt, 1);
            idx_out[be * CK + pos] = s;
            g_out[be * CK + pos] = p[j] * inv_total;
        } else if (uv[j] == v) {
            const int pos = atomicAdd(&eqc, 1);
            eqbuf[pos] = s;
        }
    }
    __syncthreads();
    if (tid == 0) {
        const int cgt = scnt;              // count strictly greater (< 256)
        const int quota = CK - cgt;        // >= 1
        const int n = eqc;                 // >= quota
        const float gv = __uint_as_float(v) * inv_total;
        if (n > quota) {
            // lowest-index tie-break (matches jax.lax.top_k): pick smallest indices
            for (int i = 0; i < quota; i++) {
                int mn = i;
                for (int k2 = i + 1; k2 < n; k2++)
                    if (eqbuf[k2] < eqbuf[mn]) mn = k2;
                const int t2 = eqbuf[i]; eqbuf[i] = eqbuf[mn]; eqbuf[mn] = t2;
            }
        }
        for (int i = 0; i < quota; i++) {
            idx_out[be * CK + cgt + i] = eqbuf[i];
            g_out[be * CK + cgt + i] = gv;
        }
    }
}

// ---------------- K3: gather selected tokens, convert to bf16 ----------------
__global__ void gather_kernel(const float* __restrict__ x,
                              const int* __restrict__ idx_ws,
                              unsigned short* __restrict__ xinbuf) {
    const int row = blockIdx.x;            // be*CK + slot
    const int be = row >> 8;
    const int b = be >> 4;
    const int tok = idx_ws[row];
    const int c0 = threadIdx.x * 4;
    const f32x4 f = *(const f32x4*)(x + ((size_t)b * CS + tok) * CD + c0);
    union { unsigned short u[4]; uint2 v; } t;
    t.u[0] = f2bf(f[0]); t.u[1] = f2bf(f[1]); t.u[2] = f2bf(f[2]); t.u[3] = f2bf(f[3]);
    *(uint2*)(xinbuf + (size_t)row * CD + c0) = t.v;
}

// ---------------- K4/K5: batched GEMM 256x1024x1024 per (b,e) ----------------
// PHASE 0: h = relu(xin @ W1 + b1) -> hout (bf16)
// PHASE 1: out = (h @ W2 + b2) * g  -> atomicAdd scatter into y
template <int PHASE>
__global__ __launch_bounds__(256, 2)
void ffn_gemm(const unsigned short* __restrict__ Ain,  // bf16 [be][256][1024]
              const float* __restrict__ W,             // fp32 [E][1024][1024]
              const float* __restrict__ bias,          // b1 (E*D) or b2 (D)
              unsigned short* __restrict__ hout,       // phase 0 output
              const int* __restrict__ idx_ws,
              const float* __restrict__ g_ws,
              float* __restrict__ y) {
    const int mtile = blockIdx.x;   // 0..1
    const int ntile = blockIdx.y;   // 0..7
    const int be = blockIdx.z;      // 0..31
    const int b = be >> 4, e = be & 15;
    const int tid = threadIdx.x;
    const int w = tid >> 6, l = tid & 63;
    const int wm = w & 1, wn = w >> 1;
    const int quad = l >> 4, lr = l & 15;

    // padded pitch 40 bf16 (80B): frag ds_read_b128 lands ~2-way (free)
    __shared__ __align__(16) unsigned short As[128 * 40];
    __shared__ __align__(16) unsigned short Bs[128 * 40];

    f32x4 acc[4][4];
    const f32x4 zz = {0.f, 0.f, 0.f, 0.f};
#pragma unroll
    for (int mi = 0; mi < 4; mi++)
#pragma unroll
        for (int ni = 0; ni < 4; ni++) acc[mi][ni] = zz;

    // A staging: thread -> (row = p*64 + tid/4, col = (tid%4)*8), 16B bf16 copy
    const int arow = tid >> 2;
    const int acol = (tid & 3) << 3;
    const unsigned short* aptr[2];
#pragma unroll
    for (int p = 0; p < 2; p++)
        aptr[p] = Ain + ((size_t)be * CK + mtile * 128 + p * 64 + arow) * CD + acol;

    // B staging: thread -> n = tid%128, k-half = tid/128; 16 strided fp32 loads,
    // convert, write transposed Bs[n][k] as 2x ds_write_b128
    const int bn = tid & 127;
    const int bh = tid >> 7;
    const float* wsrc = W + (size_t)e * CD * CD + (size_t)(bh * 16) * CD + ntile * 128 + bn;

    for (int ks = 0; ks < CD / 32; ks++) {
        const int k0 = ks * 32;
#pragma unroll
        for (int p = 0; p < 2; p++) {
            union { unsigned short u[8]; uint4 v; } t;
            t.v = *(const uint4*)(aptr[p] + k0);
            *(uint4*)(&As[(p * 64 + arow) * 40 + acol]) = t.v;
        }
        {
            union { unsigned short u[16]; uint4 v[2]; } t;
            const float* s0 = wsrc + (size_t)k0 * CD;
#pragma unroll
            for (int kk = 0; kk < 16; kk++) t.u[kk] = f2bf(s0[(size_t)kk * CD]);
            *(uint4*)(&Bs[bn * 40 + bh * 16]) = t.v[0];
            *(uint4*)(&Bs[bn * 40 + bh * 16 + 8]) = t.v[1];
        }
        __syncthreads();

        bf16x8 af[4], bf[4];
#pragma unroll
        for (int mi = 0; mi < 4; mi++)
            af[mi] = *(const bf16x8*)&As[(wm * 64 + mi * 16 + lr) * 40 + quad * 8];
#pragma unroll
        for (int ni = 0; ni < 4; ni++)
            bf[ni] = *(const bf16x8*)&Bs[(wn * 64 + ni * 16 + lr) * 40 + quad * 8];
#pragma unroll
        for (int mi = 0; mi < 4; mi++)
#pragma unroll
            for (int ni = 0; ni < 4; ni++)
                acc[mi][ni] = __builtin_amdgcn_mfma_f32_16x16x32_bf16(
                    af[mi], bf[ni], acc[mi][ni], 0, 0, 0);
        __syncthreads();
    }

    // epilogue. C/D layout: col = lane&15, row = quad*4 + r  (m89/m91 verified)
    const int gn_base = ntile * 128 + wn * 64;
    if (PHASE == 0) {
#pragma unroll
        for (int mi = 0; mi < 4; mi++)
#pragma unroll
            for (int r = 0; r < 4; r++) {
                const int slot = mtile * 128 + wm * 64 + mi * 16 + quad * 4 + r;
                unsigned short* outrow = hout + ((size_t)be * CK + slot) * CD;
#pragma unroll
                for (int ni = 0; ni < 4; ni++) {
                    const int col = gn_base + ni * 16 + lr;
                    float hv = acc[mi][ni][r] + bias[e * CD + col];
                    hv = fmaxf(hv, 0.0f);
                    outrow[col] = f2bf(hv);
                }
            }
    } else {
#pragma unroll
        for (int mi = 0; mi < 4; mi++)
#pragma unroll
            for (int r = 0; r < 4; r++) {
                const int slot = mtile * 128 + wm * 64 + mi * 16 + quad * 4 + r;
                const int tok = idx_ws[be * CK + slot];
                const float gval = g_ws[be * CK + slot];
                float* yrow = y + ((size_t)b * CS + tok) * CD;
#pragma unroll
                for (int ni = 0; ni < 4; ni++) {
                    const int col = gn_base + ni * 16 + lr;
                    const float val = (acc[mi][ni][r] + bias[col]) * gval;
                    atomicAdd(&yrow[col], val);
                }
            }
    }
}

extern "C" void kernel_launch(void* const* d_in, const int* in_sizes, int n_in,
                              void* d_out, int out_size, void* d_ws, size_t ws_size,
                              hipStream_t stream) {
    const float* x    = (const float*)d_in[0];
    const float* gate = (const float*)d_in[1];
    const float* W1   = (const float*)d_in[2];
    const float* b1   = (const float*)d_in[3];
    const float* W2   = (const float*)d_in[4];
    const float* b2   = (const float*)d_in[5];
    float* y = (float*)d_out;

    // workspace layout (bytes):
    //   logits: 0           .. 262144   (B*S*E fp32)
    //   idx_ws: 262144      .. +32768   (B*E*K int)
    //   g_ws:   294912      .. +32768   (B*E*K fp32)
    //   xinbuf: 327680      .. +16.78MB (B*E*K*D bf16)
    //   hbuf:   17104896    .. +16.78MB (B*E*K*D bf16)
    char* ws = (char*)d_ws;
    float* logits = (float*)ws;
    int* idxw = (int*)(ws + 262144);
    float* gw = (float*)(ws + 262144 + 32768);
    unsigned short* xinbuf = (unsigned short*)(ws + 262144 + 65536);
    unsigned short* hbuf = (unsigned short*)(ws + 262144 + 65536 + (size_t)CB * CE * CK * CD * 2);

    logits_kernel<<<CB * CS, 64, 0, stream>>>(x, gate, logits);
    topk_kernel<<<CB * CE, 256, 0, stream>>>(logits, idxw, gw);
    gather_kernel<<<CB * CE * CK, 256, 0, stream>>>(x, idxw, xinbuf);
    hipMemsetAsync(d_out, 0, (size_t)CB * CS * CD * sizeof(float), stream);
    ffn_gemm<0><<<dim3(2, 8, CB * CE), 256, 0, stream>>>(xinbuf, W1, b1, hbuf, idxw, gw, y);
    ffn_gemm<1><<<dim3(2, 8, CB * CE), 256, 0, stream>>>(hbuf, W2, b2, nullptr, idxw, gw, y);
}

// Round 2
// 302.793 us; speedup vs baseline: 1.0231x; 1.0231x over previous
//
#include <hip/hip_runtime.h>
#include <stdint.h>
#include <math.h>

// Problem constants (fixed by the reference)
constexpr int CB = 2;      // batch
constexpr int CS = 2048;   // seq (cutoff)
constexpr int CD = 1024;   // dmodel
constexpr int CE = 16;     // experts
constexpr int CK = 256;    // topk

typedef short bf16x8 __attribute__((ext_vector_type(8)));
typedef float f32x4 __attribute__((ext_vector_type(4)));

typedef __attribute__((address_space(1))) const unsigned int gu32;
typedef __attribute__((address_space(3))) unsigned int lu32;

__device__ __forceinline__ void async16(const void* g, void* l) {
    __builtin_amdgcn_global_load_lds((gu32*)g, (lu32*)l, 16, 0, 0);
}

__device__ inline unsigned short f2bf(float f) {
    union { float f; uint32_t u; } v; v.f = f;
    uint32_t u = v.u;
    uint32_t r = (u + 0x7FFFu + ((u >> 16) & 1u)) >> 16;
    return (unsigned short)r;
}

// ---------------- K1: logits[b,s,e] = dot(x[b,s,:], gate[:,e]) ----------------
__global__ void logits_kernel(const float* __restrict__ x,
                              const float* __restrict__ gate,
                              float* __restrict__ logits) {
    const int bs = blockIdx.x;      // 0..B*S-1
    const int l = threadIdx.x;      // 0..63
    const float* xr = x + (size_t)bs * CD;
    float acc[CE];
#pragma unroll
    for (int e = 0; e < CE; e++) acc[e] = 0.0f;
    for (int i = 0; i < CD / 64; i++) {
        const int d = i * 64 + l;
        const float xv = xr[d];
        const float* g = gate + (size_t)d * CE;
#pragma unroll
        for (int e = 0; e < CE; e++) acc[e] += xv * g[e];
    }
#pragma unroll
    for (int e = 0; e < CE; e++) {
        float v = acc[e];
#pragma unroll
        for (int o = 32; o > 0; o >>= 1) v += __shfl_down(v, o);
        if (l == 0) logits[(size_t)bs * CE + e] = v;
    }
}

// ---------------- K2: per (b,e) softmax over tokens + top-256 ----------------
// radix-256 select over the uint bit patterns of p = exp(l - max) (all > 0,
// so uint order == float order). 4 passes of histogram + suffix-scan.
__global__ void topk_kernel(const float* __restrict__ logits,
                            int* __restrict__ idx_out,
                            float* __restrict__ g_out) {
    const int be = blockIdx.x;            // b*E + e
    const int b = be >> 4, e = be & 15;
    const int tid = threadIdx.x;          // 256
    const int lane = tid & 63, wid = tid >> 6;

    __shared__ float redf[4];
    __shared__ int hist[256];
    __shared__ int wsum[4];
    __shared__ int sh_bin, sh_rank;
    __shared__ int scnt, eqc;
    __shared__ int eqbuf[CS];

    float lv[8], p[8];
    unsigned int uv[8];
#pragma unroll
    for (int j = 0; j < 8; j++) {
        const int s = tid + j * 256;
        lv[j] = logits[((size_t)(b * CS + s)) * CE + e];
    }
    // block max
    float m = lv[0];
#pragma unroll
    for (int j = 1; j < 8; j++) m = fmaxf(m, lv[j]);
#pragma unroll
    for (int o = 32; o > 0; o >>= 1) m = fmaxf(m, __shfl_down(m, o));
    if (lane == 0) redf[wid] = m;
    __syncthreads();
    m = fmaxf(fmaxf(redf[0], redf[1]), fmaxf(redf[2], redf[3]));
    __syncthreads();
    // exp + sum
    float lsum = 0.0f;
#pragma unroll
    for (int j = 0; j < 8; j++) {
        p[j] = expf(lv[j] - m);
        uv[j] = __float_as_uint(p[j]);
        lsum += p[j];
    }
#pragma unroll
    for (int o = 32; o > 0; o >>= 1) lsum += __shfl_down(lsum, o);
    if (lane == 0) redf[wid] = lsum;
    __syncthreads();
    const float total = redf[0] + redf[1] + redf[2] + redf[3];
    const float inv_total = 1.0f / total;

    // ---- radix-256 select: find v = CK-th largest bit pattern ----
    unsigned int prefix = 0;
    int kneed = CK;
    for (int pass = 0; pass < 4; pass++) {
        const int shift = 24 - 8 * pass;
        __syncthreads();
        hist[tid] = 0;
        __syncthreads();
        const unsigned int hmask = (pass == 0) ? 0u : (0xFFFFFFFFu << (shift + 8));
#pragma unroll
        for (int j = 0; j < 8; j++)
            if ((uv[j] & hmask) == prefix)
                atomicAdd(&hist[(uv[j] >> shift) & 255], 1);
        __syncthreads();
        const int own = hist[tid];
        // wave-level inclusive suffix scan over bins (bin index = tid)
        int s = own;
#pragma unroll
        for (int o = 1; o < 64; o <<= 1) {
            int t = __shfl_down(s, o);
            if (lane + o < 64) s += t;
        }
        if (lane == 0) wsum[wid] = s;
        __syncthreads();
        int above = 0;
        for (int ww = wid + 1; ww < 4; ww++) above += wsum[ww];
        const int incl = s + above;  // count of candidates with bin >= tid
        if (incl >= kneed && (incl - own) < kneed) {
            sh_bin = tid;
            sh_rank = kneed - (incl - own);
        }
        __syncthreads();
        prefix |= ((unsigned int)sh_bin) << shift;
        kneed = sh_rank;
    }
    const unsigned int v = prefix;   // exact bit pattern of the CK-th largest
    const int quota = kneed;         // how many values == v to take

    if (tid == 0) { scnt = 0; eqc = 0; }
    __syncthreads();
#pragma unroll
    for (int j = 0; j < 8; j++) {
        const int s = tid + j * 256;
        if (uv[j] > v) {
            const int pos = atomicAdd(&scnt, 1);
            idx_out[be * CK + pos] = s;
            g_out[be * CK + pos] = p[j] * inv_total;
        } else if (uv[j] == v) {
            const int pos = atomicAdd(&eqc, 1);
            eqbuf[pos] = s;
        }
    }
    __syncthreads();
    if (tid == 0) {
        const int cgt = scnt;              // strictly greater count == CK - quota
        const int n = eqc;
        const float gv = __uint_as_float(v) * inv_total;
        if (n > quota) {
            // lowest-index tie-break (matches jax.lax.top_k)
            for (int i = 0; i < quota; i++) {
                int mn = i;
                for (int k2 = i + 1; k2 < n; k2++)
                    if (eqbuf[k2] < eqbuf[mn]) mn = k2;
                const int t2 = eqbuf[i]; eqbuf[i] = eqbuf[mn]; eqbuf[mn] = t2;
            }
        }
        for (int i = 0; i < quota; i++) {
            idx_out[be * CK + cgt + i] = eqbuf[i];
            g_out[be * CK + cgt + i] = gv;
        }
    }
}

// ---------------- K3: gather selected tokens, convert to bf16 ----------------
__global__ void gather_kernel(const float* __restrict__ x,
                              const int* __restrict__ idx_ws,
                              unsigned short* __restrict__ xinbuf) {
    const int row = blockIdx.x;            // be*CK + slot
    const int be = row >> 8;
    const int b = be >> 4;
    const int tok = idx_ws[row];
    const int c0 = threadIdx.x * 4;
    const f32x4 f = *(const f32x4*)(x + ((size_t)b * CS + tok) * CD + c0);
    union { unsigned short u[4]; uint2 v; } t;
    t.u[0] = f2bf(f[0]); t.u[1] = f2bf(f[1]); t.u[2] = f2bf(f[2]); t.u[3] = f2bf(f[3]);
    *(uint2*)(xinbuf + (size_t)row * CD + c0) = t.v;
}

// ---------------- K4: transpose+convert W[e][k][n] fp32 -> Wt[e][n][k] bf16 ----
// 64x64 tiles through LDS; 16-short chunk XOR swizzle keeps conflicts <=4-way.
__global__ __launch_bounds__(256)
void wt_kernel(const float* __restrict__ W, unsigned short* __restrict__ Wt) {
    const int kt = blockIdx.x, nt = blockIdx.y, e = blockIdx.z;
    const float* src = W + (size_t)e * CD * CD;
    unsigned short* dst = Wt + (size_t)e * CD * CD;
    const int tid = threadIdx.x;
    __shared__ unsigned short T[64 * 64];

    const int kr = tid >> 4;            // 0..15
    const int n4 = (tid & 15) << 2;     // 0,4,..,60
#pragma unroll
    for (int it = 0; it < 4; it++) {
        const int k = it * 16 + kr;                    // tile-local k 0..63
        const f32x4 v = *(const f32x4*)(src + (size_t)(kt * 64 + k) * CD + nt * 64 + n4);
        const int pp = k >> 4;                          // 16-short chunk 0..3
        const int klo = k & 15;
#pragma unroll
        for (int i = 0; i < 4; i++) {
            const int n = n4 + i;
            T[n * 64 + ((pp ^ ((n >> 2) & 3)) << 4) + klo] = f2bf(v[i]);
        }
    }
    __syncthreads();
    const int n = tid >> 2;             // 0..63
    const int pp = tid & 3;             // output k-chunk
    const int sw = pp ^ ((n >> 2) & 3);
    const uint4 a = *(const uint4*)&T[n * 64 + (sw << 4)];
    const uint4 b = *(const uint4*)&T[n * 64 + (sw << 4) + 8];
    unsigned short* drow = dst + (size_t)(nt * 64 + n) * CD + kt * 64 + pp * 16;
    *(uint4*)drow = a;
    *(uint4*)(drow + 8) = b;
}

// ---------------- K5/K6: batched GEMM 256x1024x1024 per (b,e), m97-style ------
// A bf16 [be][256][1024] k-contig; B = Wt bf16 [e][n][k] k-contig.
// global_load_lds width-16 staging, 128x128 tile, BK=32, 4 waves x 4x4 frags.
template <int PHASE>
__global__ __launch_bounds__(256, 2)
void ffn_gemm(const unsigned short* __restrict__ Ain,
              const unsigned short* __restrict__ Wt,
              const float* __restrict__ bias,
              unsigned short* __restrict__ hout,
              const int* __restrict__ idx_ws,
              const float* __restrict__ g_ws,
              float* __restrict__ y) {
    const int mtile = blockIdx.x;   // 0..1
    const int ntile = blockIdx.y;   // 0..7
    const int z = blockIdx.z;       // 0..31 ; adjacent z share expert (L2 reuse)
    const int e = z >> 1, b = z & 1;
    const int be = b * 16 + e;
    const int tid = threadIdx.x;
    const int w = tid >> 6, l = tid & 63;
    const int wm = w & 1, wn = w >> 1;
    const int quad = l >> 4, lr = l & 15;

    // unpadded pitch 32 bf16 (64B) — required by global_load_lds lane order
    __shared__ __align__(16) unsigned short As[128 * 32];
    __shared__ __align__(16) unsigned short Bs[128 * 32];

    f32x4 acc[4][4];
    const f32x4 zz = {0.f, 0.f, 0.f, 0.f};
#pragma unroll
    for (int mi = 0; mi < 4; mi++)
#pragma unroll
        for (int ni = 0; ni < 4; ni++) acc[mi][ni] = zz;

    // staging map: instr j of wave w covers LDS rows (w*2+j)*16 + l/4, chunk l%4
    const int sr = l >> 2;
    const int sc = l & 3;
    const unsigned short* Abase = Ain + ((size_t)be * CK + mtile * 128) * CD;
    const unsigned short* Bbase = Wt + ((size_t)e * CD + ntile * 128) * CD;

    for (int k0 = 0; k0 < CD; k0 += 32) {
#pragma unroll
        for (int j = 0; j < 2; j++) {
            const int row = (w * 2 + j) * 16 + sr;
            const size_t goff = (size_t)row * CD + k0 + sc * 8;
            const int loff = (w * 2 + j) * 512 + l * 8;   // shorts
            async16(Abase + goff, &As[loff]);
            async16(Bbase + goff, &Bs[loff]);
        }
        __syncthreads();

        bf16x8 af[4], bf[4];
#pragma unroll
        for (int mi = 0; mi < 4; mi++)
            af[mi] = *(const bf16x8*)&As[(wm * 64 + mi * 16 + lr) * 32 + quad * 8];
#pragma unroll
        for (int ni = 0; ni < 4; ni++)
            bf[ni] = *(const bf16x8*)&Bs[(wn * 64 + ni * 16 + lr) * 32 + quad * 8];
#pragma unroll
        for (int mi = 0; mi < 4; mi++)
#pragma unroll
            for (int ni = 0; ni < 4; ni++)
                acc[mi][ni] = __builtin_amdgcn_mfma_f32_16x16x32_bf16(
                    af[mi], bf[ni], acc[mi][ni], 0, 0, 0);
        __syncthreads();
    }

    // epilogue. C/D layout: col = lane&15, row = quad*4 + r  (m89/m91 verified)
    const int gn_base = ntile * 128 + wn * 64;
    if (PHASE == 0) {
#pragma unroll
        for (int mi = 0; mi < 4; mi++)
#pragma unroll
            for (int r = 0; r < 4; r++) {
                const int slot = mtile * 128 + wm * 64 + mi * 16 + quad * 4 + r;
                unsigned short* outrow = hout + ((size_t)be * CK + slot) * CD;
#pragma unroll
                for (int ni = 0; ni < 4; ni++) {
                    const int col = gn_base + ni * 16 + lr;
                    float hv = acc[mi][ni][r] + bias[e * CD + col];
                    hv = fmaxf(hv, 0.0f);
                    outrow[col] = f2bf(hv);
                }
            }
    } else {
#pragma unroll
        for (int mi = 0; mi < 4; mi++)
#pragma unroll
            for (int r = 0; r < 4; r++) {
                const int slot = mtile * 128 + wm * 64 + mi * 16 + quad * 4 + r;
                const int tok = idx_ws[be * CK + slot];
                const float gval = g_ws[be * CK + slot];
                float* yrow = y + ((size_t)b * CS + tok) * CD;
#pragma unroll
                for (int ni = 0; ni < 4; ni++) {
                    const int col = gn_base + ni * 16 + lr;
                    const float val = (acc[mi][ni][r] + bias[col]) * gval;
                    atomicAdd(&yrow[col], val);
                }
            }
    }
}

extern "C" void kernel_launch(void* const* d_in, const int* in_sizes, int n_in,
                              void* d_out, int out_size, void* d_ws, size_t ws_size,
                              hipStream_t stream) {
    const float* x    = (const float*)d_in[0];
    const float* gate = (const float*)d_in[1];
    const float* W1   = (const float*)d_in[2];
    const float* b1   = (const float*)d_in[3];
    const float* W2   = (const float*)d_in[4];
    const float* b2   = (const float*)d_in[5];
    float* y = (float*)d_out;

    // workspace layout (bytes):
    //   logits: 0         .. 262144     (B*S*E fp32)
    //   idx:    262144    .. +32768
    //   g:      294912    .. +32768
    //   xin:    327680    .. +16.78MB   (bf16)
    //   hbuf:   17104896  .. +16.78MB   (bf16)
    //   Wt:     33882112  .. +33.55MB   (bf16, W1 then reused for W2)
    char* ws = (char*)d_ws;
    float* logits = (float*)ws;
    int* idxw = (int*)(ws + 262144);
    float* gw = (float*)(ws + 294912);
    unsigned short* xinbuf = (unsigned short*)(ws + 327680);
    unsigned short* hbuf = (unsigned short*)(ws + 17104896);
    unsigned short* wtbuf = (unsigned short*)(ws + 33882112);

    logits_kernel<<<CB * CS, 64, 0, stream>>>(x, gate, logits);
    topk_kernel<<<CB * CE, 256, 0, stream>>>(logits, idxw, gw);
    gather_kernel<<<CB * CE * CK, 256, 0, stream>>>(x, idxw, xinbuf);
    wt_kernel<<<dim3(16, 16, CE), 256, 0, stream>>>(W1, wtbuf);
    hipMemsetAsync(d_out, 0, (size_t)CB * CS * CD * sizeof(float), stream);
    ffn_gemm<0><<<dim3(2, 8, CB * CE), 256, 0, stream>>>(xinbuf, wtbuf, b1, hbuf, idxw, gw, y);
    wt_kernel<<<dim3(16, 16, CE), 256, 0, stream>>>(W2, wtbuf);
    ffn_gemm<1><<<dim3(2, 8, CB * CE), 256, 0, stream>>>(hbuf, wtbuf, b2, nullptr, idxw, gw, y);
}